// Round 2
// 445.408 us; speedup vs baseline: 1.0373x; 1.0373x over previous
//
#include <hip/hip_runtime.h>

typedef __attribute__((ext_vector_type(8))) short s8v;
typedef __attribute__((ext_vector_type(4))) short s4v;
typedef __attribute__((ext_vector_type(4))) float f4v;

#define DEV __device__ __forceinline__

DEV short b16(float f) {
  unsigned u = __builtin_bit_cast(unsigned, f);
  u = (u + 0x7fffu + ((u >> 16) & 1u)) >> 16;
  return (short)u;
}

// packed f32x2 -> bf16x2 (RNE) as one uint
DEV unsigned pk2(float a, float b) {
#if __has_builtin(__builtin_amdgcn_cvt_pk_bf16_f32)
  auto p = __builtin_amdgcn_cvt_pk_bf16_f32(a, b);
  return __builtin_bit_cast(unsigned, p);
#else
  return (unsigned)(unsigned short)b16(a) | ((unsigned)(unsigned short)b16(b) << 16);
#endif
}

DEV float fexp2(float x) {
#if __has_builtin(__builtin_amdgcn_exp2f)
  return __builtin_amdgcn_exp2f(x);
#else
  return exp2f(x);
#endif
}

// async global->LDS, 16B per lane; lds base must be wave-uniform
DEV void gl_lds16(const short* g, short* l) {
  __builtin_amdgcn_global_load_lds((const __attribute__((address_space(1))) void*)g,
                                   (__attribute__((address_space(3))) void*)l, 16, 0, 0);
}

// ---------------- cast x: fp32 -> bf16
__global__ __launch_bounds__(256) void cast_f32_bf16(const float* __restrict__ in,
                                                     short* __restrict__ out, int n4) {
  int i = blockIdx.x * 256 + threadIdx.x;
  if (i >= n4) return;
  float4 v = ((const float4*)in)[i];
  s4v o; o.x = b16(v.x); o.y = b16(v.y); o.z = b16(v.z); o.w = b16(v.w);
  ((s4v*)out)[i] = o;
}

// ---------------- transpose-cast W [1024 k][1024 n] fp32 -> Wt [n][k] bf16
__global__ __launch_bounds__(256) void wtrans(const float* __restrict__ W, short* __restrict__ Wt) {
  int id = blockIdx.x * 256 + threadIdx.x;
  int k8 = id >> 10;
  int n  = id & 1023;
  s8v o;
#pragma unroll
  for (int j = 0; j < 8; ++j) o[j] = b16(W[(k8 * 8 + j) * 1024 + n]);
  *(s8v*)&Wt[n * 1024 + k8 * 8] = o;
}

// ---------------- GEMM: C[8192x1024] = (A(bf16) x Bt^T + bias) * scale; global_load_lds staging
template <bool OUT_BF16>
__global__ __launch_bounds__(256) void gemm128(const short* __restrict__ A,
                                               const short* __restrict__ Bt,
                                               const float* __restrict__ bias,
                                               void* __restrict__ Cout, float scale) {
  __shared__ short As[128 * 64];
  __shared__ short Bs[128 * 64];
  const int tid = threadIdx.x;
  const int w = tid >> 6, lane = tid & 63, quad = lane >> 4, l15 = lane & 15;
  const int wm = w >> 1, wn = w & 1;
  const int m0 = blockIdx.y * 128, n0 = blockIdx.x * 128;
  const int lr = lane >> 3, lc = (lane & 7) * 8;
  f4v acc[4][4] = {};
  for (int k0 = 0; k0 < 1024; k0 += 64) {
#pragma unroll
    for (int i = 0; i < 4; ++i) {
      int c = i * 4 + w;
      int r = c * 8 + lr;
      gl_lds16(&A[(m0 + r) * 1024 + k0 + lc], &As[c * 512]);
      gl_lds16(&Bt[(n0 + r) * 1024 + k0 + lc], &Bs[c * 512]);
    }
    __syncthreads();
#pragma unroll
    for (int kk = 0; kk < 2; ++kk) {
      s8v af[4], bf[4];
#pragma unroll
      for (int mt = 0; mt < 4; ++mt) af[mt] = *(const s8v*)&As[(wm * 64 + mt * 16 + l15) * 64 + kk * 32 + quad * 8];
#pragma unroll
      for (int nt = 0; nt < 4; ++nt) bf[nt] = *(const s8v*)&Bs[(wn * 64 + nt * 16 + l15) * 64 + kk * 32 + quad * 8];
#pragma unroll
      for (int mt = 0; mt < 4; ++mt)
#pragma unroll
        for (int nt = 0; nt < 4; ++nt)
          acc[mt][nt] = __builtin_amdgcn_mfma_f32_16x16x32_bf16(af[mt], bf[nt], acc[mt][nt], 0, 0, 0);
    }
    __syncthreads();
  }
#pragma unroll
  for (int nt = 0; nt < 4; ++nt) {
    const int col = n0 + wn * 64 + nt * 16 + l15;
    const float bcol = bias[col];
#pragma unroll
    for (int mt = 0; mt < 4; ++mt)
#pragma unroll
      for (int r = 0; r < 4; ++r) {
        const int row = m0 + wm * 64 + mt * 16 + quad * 4 + r;
        float v = (acc[mt][nt][r] + bcol) * scale;
        if (OUT_BF16) ((short*)Cout)[row * 1024 + col] = b16(v);
        else          ((float*)Cout)[row * 1024 + col] = v;
      }
  }
}

// ---------------- V transpose: Vb [b,s,h,d] -> Vt [b,h,d,s]
__global__ __launch_bounds__(256) void vtrans(const short* __restrict__ V, short* __restrict__ Vt) {
  __shared__ short T[128][72];
  const int st = blockIdx.x, h = blockIdx.y, b = blockIdx.z;
  const int tid = threadIdx.x;
#pragma unroll
  for (int i = 0; i < 4; ++i) {
    int c = tid + i * 256;
    int r = c >> 3, c8 = (c & 7) * 8;
    *(s8v*)&T[r][c8] = *(const s8v*)&V[((b * 2048 + st * 128 + r) * 16 + h) * 64 + c8];
  }
  __syncthreads();
#pragma unroll
  for (int i = 0; i < 4; ++i) {
    int id = tid + i * 256;
    int d = id & 63, s8 = id >> 6;
    s8v o;
#pragma unroll
    for (int j = 0; j < 8; ++j) o[j] = T[s8 * 8 + j][d];
    *(s8v*)&Vt[((b * 16 + h) * 64 + d) * 2048 + st * 128 + s8 * 8] = o;
  }
}

// ---------------- fused attention v5: async global_load_lds staging with PRE-SWIZZLED
// global source (LDS stays linear-dest, swizzled reads unchanged). Q pre-scaled by
// C2=(1/8)log2(e) in its projection GEMM, so score exp is exp2(st) directly.
__global__ __launch_bounds__(256, 3) void attn_ctx(const short* __restrict__ Q, const short* __restrict__ K,
                                                   const short* __restrict__ Vt,
                                                   float* __restrict__ rbuf, short* __restrict__ ctx) {
  __shared__ __align__(16) char smem[50432];
  short* Ks = (short*)smem;                 // [128 kpos][64 d]   swizzled, 16384 B
  short* Vs = (short*)(smem + 16384);       // [64 d][128 kpos]   swizzled, 16384 B
  short* Ps = (short*)(smem + 32768);       // [64 q][128 kpos]   swizzled, 16384 B
  short* Qs = Ps;                           // alias: Qs dead after frag hoist
  float* l_part = (float*)(smem + 49152);   // [4 waves][64 q]
  float* l_s    = (float*)(smem + 50176);   // [64 q] -> 1/l
  const int q64 = blockIdx.x, h = blockIdx.y, b = blockIdx.z;
  const int tid = threadIdx.x, w = tid >> 6, lane = tid & 63, quad = lane >> 4, l15 = lane & 15;
  const int bh = b * 16 + h, q0 = q64 * 64;

  // stage Q tile (64x64) swizzled (reg roundtrip; once per kernel)
#pragma unroll
  for (int i = 0; i < 2; ++i) {
    int c = tid + i * 256;
    int r = c >> 3, cc = c & 7;
    *(s8v*)&Qs[r * 64 + (((cc ^ (r & 7))) << 3)] =
        *(const s8v*)&Q[((b * 2048 + q0 + r) * 16 + h) * 64 + cc * 8];
  }
  __syncthreads();
  // hoist Q fragments (B-operand of St = K·Q^T), all 64 q cols
  s8v qf[4][2];
#pragma unroll
  for (int nt = 0; nt < 4; ++nt) {
    int r = nt * 16 + l15;
    qf[nt][0] = *(const s8v*)&Qs[r * 64 + ((quad ^ (r & 7)) << 3)];
    qf[nt][1] = *(const s8v*)&Qs[r * 64 + (((4 + quad) ^ (r & 7)) << 3)];
  }
  const short* kbase = &K[((long)(b * 2048) * 16 + h) * 64];
  const short* vbase = &Vt[(long)(bh * 64) * 2048];
  // per-lane pre-swizzled staging sources:
  // K: LDS linear chunk p = j*64+lane (j=i*4+w); row r = j*8+(lane>>3); stored chunk
  // sc=lane&7 holds logical chunk sc^(r&7) -> global col chunk (lane&7)^(lane>>3).
  const int krow = w * 8 + (lane >> 3);
  const short* ksrc = kbase + krow * 1024 + (((lane & 7) ^ (lane >> 3)) << 3);
  // V: row d = j*4+(lane>>4); stored chunk sc=lane&15 holds logical sc^(d&15)
  // -> global col chunk (lane&15)^(w*4+(lane>>4)).
  const int vrow = w * 4 + (lane >> 4);
  const short* vsrc = vbase + vrow * 2048 + (((lane & 15) ^ vrow) << 3);
  f4v o[4] = {};
  float l_acc[4] = {0.f, 0.f, 0.f, 0.f};

  for (int kt = 0; kt < 16; ++kt) {
    __syncthreads();
    // async-stage K tile [128 kpos][64 d] and V tile [64 d][128 kpos] (pre-swizzled src)
#pragma unroll
    for (int i = 0; i < 4; ++i) {
      gl_lds16(ksrc + kt * 131072 + i * 32768, &Ks[(i * 4 + w) * 512]);
      gl_lds16(vsrc + kt * 128 + i * 32768, &Vs[(i * 4 + w) * 512]);
    }
    __syncthreads();
    // score phase: wave w computes St rows kpos [w*32, w*32+32), all 64 q
#pragma unroll
    for (int mt = 0; mt < 2; ++mt) {
      int kr = w * 32 + mt * 16 + l15;
      s8v a0 = *(const s8v*)&Ks[kr * 64 + ((quad ^ (kr & 7)) << 3)];
      s8v a1 = *(const s8v*)&Ks[kr * 64 + (((4 + quad) ^ (kr & 7)) << 3)];
#pragma unroll
      for (int nt = 0; nt < 4; ++nt) {
        f4v st = {};
        st = __builtin_amdgcn_mfma_f32_16x16x32_bf16(a0, qf[nt][0], st, 0, 0, 0);
        st = __builtin_amdgcn_mfma_f32_16x16x32_bf16(a1, qf[nt][1], st, 0, 0, 0);
        float e0 = fexp2(st[0]), e1 = fexp2(st[1]);
        float e2 = fexp2(st[2]), e3 = fexp2(st[3]);
        l_acc[nt] += (e0 + e1) + (e2 + e3);
        uint2 pp; pp.x = pk2(e0, e1); pp.y = pk2(e2, e3);
        int q = nt * 16 + l15;
        // kpos = w*32 + mt*16 + quad*4 ; chunk = kpos>>3, within = kpos&7
        int chunk = (w * 4 + mt * 2 + (quad >> 1)) ^ l15;
        *(uint2*)&Ps[q * 128 + (chunk << 3) + (quad & 1) * 4] = pp;
      }
    }
    __syncthreads();
    // PV phase: wave w owns q rows [w*16, w*16+16), full 128 kpos
#pragma unroll
    for (int kk = 0; kk < 4; ++kk) {
      int qr = w * 16 + l15;
      s8v a = *(const s8v*)&Ps[qr * 128 + (((kk * 4 + quad) ^ (qr & 15)) << 3)];
#pragma unroll
      for (int dt = 0; dt < 4; ++dt) {
        int d = dt * 16 + l15;
        s8v vb = *(const s8v*)&Vs[d * 128 + (((kk * 4 + quad) ^ (d & 15)) << 3)];
        o[dt] = __builtin_amdgcn_mfma_f32_16x16x32_bf16(a, vb, o[dt], 0, 0, 0);
      }
    }
  }

  // reduce l: intra-wave over quads, then cross-wave via LDS
#pragma unroll
  for (int nt = 0; nt < 4; ++nt) {
    float v = l_acc[nt];
    v += __shfl_xor(v, 16, 64);
    v += __shfl_xor(v, 32, 64);
    if (quad == 0) l_part[w * 64 + nt * 16 + l15] = v;
  }
  __syncthreads();
  if (tid < 64) {
    float s = l_part[tid] + l_part[64 + tid] + l_part[128 + tid] + l_part[192 + tid];
    float rv = 1.0f / s;
    l_s[tid] = rv;
    rbuf[bh * 2048 + q0 + tid] = rv;
  }
  __syncthreads();
  float rvq[4];
#pragma unroll
  for (int r = 0; r < 4; ++r) rvq[r] = l_s[w * 16 + quad * 4 + r];
#pragma unroll
  for (int dt = 0; dt < 4; ++dt)
#pragma unroll
    for (int r = 0; r < 4; ++r) {
      int sq = q0 + w * 16 + quad * 4 + r;
      ctx[((b * 2048 + sq) * 16 + h) * 64 + dt * 16 + l15] = b16(o[dt][r] * rvq[r]);
    }
}

// ---------------- mean over heads of probs -> [b, q, k] fp32
// async global_load_lds staging (pre-swizzled src, XOR-swizzled LDS), Q pre-scaled by C2
__global__ __launch_bounds__(256) void mean_probs(const short* __restrict__ Q, const short* __restrict__ K,
                                                  const float* __restrict__ rbuf, float* __restrict__ outm) {
  __shared__ __align__(16) short Qs[8192];   // [128 q][64 d] swizzled
  __shared__ __align__(16) short Ks[8192];   // [128 k][64 d] swizzled
  __shared__ float r_s[128];
  const int k128 = blockIdx.x, q128 = blockIdx.y, b = blockIdx.z;
  const int tid = threadIdx.x, w = tid >> 6, lane = tid & 63, quad = lane >> 4, l15 = lane & 15;
  f4v mn[2][8] = {};
  const int mrow = w * 8 + (lane >> 3);
  const int mck8 = ((lane & 7) ^ (lane >> 3)) << 3;
  const short* qsrc = Q + ((long)(b * 2048 + q128 * 128 + mrow) * 16) * 64 + mck8;
  const short* ksrc = K + ((long)(b * 2048 + k128 * 128 + mrow) * 16) * 64 + mck8;
  for (int h = 0; h < 16; ++h) {
    __syncthreads();
#pragma unroll
    for (int i = 0; i < 4; ++i) {
      gl_lds16(qsrc + h * 64 + i * 32768, &Qs[(i * 4 + w) * 512]);
      gl_lds16(ksrc + h * 64 + i * 32768, &Ks[(i * 4 + w) * 512]);
    }
    if (tid < 128) r_s[tid] = rbuf[(b * 16 + h) * 2048 + q128 * 128 + tid] * 0.0625f;
    __syncthreads();
    s8v aq[2][2];
#pragma unroll
    for (int qt = 0; qt < 2; ++qt) {
      int r = w * 32 + qt * 16 + l15;
      aq[qt][0] = *(const s8v*)&Qs[r * 64 + ((quad ^ (r & 7)) << 3)];
      aq[qt][1] = *(const s8v*)&Qs[r * 64 + (((4 + quad) ^ (r & 7)) << 3)];
    }
    float rr[2][4];
#pragma unroll
    for (int qt = 0; qt < 2; ++qt)
#pragma unroll
      for (int r = 0; r < 4; ++r) rr[qt][r] = r_s[w * 32 + qt * 16 + quad * 4 + r];
#pragma unroll
    for (int ktile = 0; ktile < 8; ++ktile) {
      int kr = ktile * 16 + l15;
      s8v b0 = *(const s8v*)&Ks[kr * 64 + ((quad ^ (kr & 7)) << 3)];
      s8v b1 = *(const s8v*)&Ks[kr * 64 + (((4 + quad) ^ (kr & 7)) << 3)];
#pragma unroll
      for (int qt = 0; qt < 2; ++qt) {
        f4v sc = {};
        sc = __builtin_amdgcn_mfma_f32_16x16x32_bf16(aq[qt][0], b0, sc, 0, 0, 0);
        sc = __builtin_amdgcn_mfma_f32_16x16x32_bf16(aq[qt][1], b1, sc, 0, 0, 0);
#pragma unroll
        for (int r = 0; r < 4; ++r)
          mn[qt][ktile][r] += fexp2(sc[r]) * rr[qt][r];
      }
    }
  }
#pragma unroll
  for (int qt = 0; qt < 2; ++qt)
#pragma unroll
    for (int ktile = 0; ktile < 8; ++ktile)
#pragma unroll
      for (int r = 0; r < 4; ++r) {
        long qrow = q128 * 128 + w * 32 + qt * 16 + quad * 4 + r;
        outm[((long)b * 2048 + qrow) * 2048 + k128 * 128 + ktile * 16 + l15] = mn[qt][ktile][r];
      }
}

extern "C" void kernel_launch(void* const* d_in, const int* in_sizes, int n_in,
                              void* d_out, int out_size, void* d_ws, size_t ws_size,
                              hipStream_t stream) {
  (void)in_sizes; (void)n_in; (void)out_size; (void)ws_size;
  const float* x  = (const float*)d_in[0];
  const float* Wq = (const float*)d_in[1];
  const float* bq = (const float*)d_in[2];
  const float* Wk = (const float*)d_in[3];
  const float* bk = (const float*)d_in[4];
  const float* Wv = (const float*)d_in[5];
  const float* bv = (const float*)d_in[6];
  const float* Wo = (const float*)d_in[7];
  const float* bo = (const float*)d_in[8];
  float* out  = (float*)d_out;
  float* outm = out + 8388608;

  char* ws = (char*)d_ws;
  short* xb  = (short*)(ws);                 // 16 MB (reused as ctx)
  short* Wqt = (short*)(ws + 16777216);
  short* Wkt = (short*)(ws + 18874368);
  short* Wvt = (short*)(ws + 20971520);
  short* Wot = (short*)(ws + 23068672);
  short* Qb  = (short*)(ws + 25165824);      // 16 MB
  short* Kb  = (short*)(ws + 41943040);      // 16 MB
  short* Vb  = (short*)(ws + 58720256);      // 16 MB (dead after vtrans)
  short* Vt  = (short*)(ws + 75497472);      // 16 MB
  float* rbuf = (float*)Vb;                  // 512 KB alias in dead Vb
  short* ctx = xb;                           // alias: xb dead after QKV GEMMs

  const float C2 = 0.18033688011112042f;     // (1/8) * log2(e), folded into Q projection

  cast_f32_bf16<<<8192, 256, 0, stream>>>(x, xb, 2097152);
  wtrans<<<512, 256, 0, stream>>>(Wq, Wqt);
  wtrans<<<512, 256, 0, stream>>>(Wk, Wkt);
  wtrans<<<512, 256, 0, stream>>>(Wv, Wvt);
  wtrans<<<512, 256, 0, stream>>>(Wo, Wot);
  dim3 gg(8, 64);
  gemm128<true><<<gg, 256, 0, stream>>>(xb, Wqt, bq, Qb, C2);     // Q pre-scaled
  gemm128<true><<<gg, 256, 0, stream>>>(xb, Wkt, bk, Kb, 1.0f);
  gemm128<true><<<gg, 256, 0, stream>>>(xb, Wvt, bv, Vb, 1.0f);
  vtrans<<<dim3(16, 16, 4), 256, 0, stream>>>(Vb, Vt);
  attn_ctx<<<dim3(32, 16, 4), 256, 0, stream>>>(Qb, Kb, Vt, rbuf, ctx);
  mean_probs<<<dim3(16, 16, 4), 256, 0, stream>>>(Qb, Kb, rbuf, outm);
  gemm128<false><<<gg, 256, 0, stream>>>(ctx, Wot, bo, out, 1.0f);
}

// Round 3
// 438.788 us; speedup vs baseline: 1.0530x; 1.0151x over previous
//
#include <hip/hip_runtime.h>

typedef __attribute__((ext_vector_type(8))) short s8v;
typedef __attribute__((ext_vector_type(4))) short s4v;
typedef __attribute__((ext_vector_type(4))) float f4v;

#define DEV __device__ __forceinline__

DEV short b16(float f) {
  unsigned u = __builtin_bit_cast(unsigned, f);
  u = (u + 0x7fffu + ((u >> 16) & 1u)) >> 16;
  return (short)u;
}

// packed f32x2 -> bf16x2 (RNE) as one uint
DEV unsigned pk2(float a, float b) {
#if __has_builtin(__builtin_amdgcn_cvt_pk_bf16_f32)
  auto p = __builtin_amdgcn_cvt_pk_bf16_f32(a, b);
  return __builtin_bit_cast(unsigned, p);
#else
  return (unsigned)(unsigned short)b16(a) | ((unsigned)(unsigned short)b16(b) << 16);
#endif
}

DEV float fexp2(float x) {
#if __has_builtin(__builtin_amdgcn_exp2f)
  return __builtin_amdgcn_exp2f(x);
#else
  return exp2f(x);
#endif
}

// async global->LDS, 16B per lane; lds base must be wave-uniform
DEV void gl_lds16(const short* g, short* l) {
  __builtin_amdgcn_global_load_lds((const __attribute__((address_space(1))) void*)g,
                                   (__attribute__((address_space(3))) void*)l, 16, 0, 0);
}

#define WAIT_VM(N) asm volatile("s_waitcnt vmcnt(" #N ")" ::: "memory")
#define WAIT_LGKM0() asm volatile("s_waitcnt lgkmcnt(0)" ::: "memory")
#define BAR() __builtin_amdgcn_s_barrier()

// ---------------- cast x: fp32 -> bf16
__global__ __launch_bounds__(256) void cast_f32_bf16(const float* __restrict__ in,
                                                     short* __restrict__ out, int n4) {
  int i = blockIdx.x * 256 + threadIdx.x;
  if (i >= n4) return;
  float4 v = ((const float4*)in)[i];
  s4v o; o.x = b16(v.x); o.y = b16(v.y); o.z = b16(v.z); o.w = b16(v.w);
  ((s4v*)out)[i] = o;
}

// ---------------- transpose-cast W [1024 k][1024 n] fp32 -> Wt [n][k] bf16
__global__ __launch_bounds__(256) void wtrans(const float* __restrict__ W, short* __restrict__ Wt) {
  int id = blockIdx.x * 256 + threadIdx.x;
  int k8 = id >> 10;
  int n  = id & 1023;
  s8v o;
#pragma unroll
  for (int j = 0; j < 8; ++j) o[j] = b16(W[(k8 * 8 + j) * 1024 + n]);
  *(s8v*)&Wt[n * 1024 + k8 * 8] = o;
}

// ---------------- GEMM: C[8192x1024] = (A(bf16) x Bt^T + bias) * scale; global_load_lds staging
template <bool OUT_BF16>
__global__ __launch_bounds__(256) void gemm128(const short* __restrict__ A,
                                               const short* __restrict__ Bt,
                                               const float* __restrict__ bias,
                                               void* __restrict__ Cout, float scale) {
  __shared__ short As[128 * 64];
  __shared__ short Bs[128 * 64];
  const int tid = threadIdx.x;
  const int w = tid >> 6, lane = tid & 63, quad = lane >> 4, l15 = lane & 15;
  const int wm = w >> 1, wn = w & 1;
  const int m0 = blockIdx.y * 128, n0 = blockIdx.x * 128;
  const int lr = lane >> 3, lc = (lane & 7) * 8;
  f4v acc[4][4] = {};
  for (int k0 = 0; k0 < 1024; k0 += 64) {
#pragma unroll
    for (int i = 0; i < 4; ++i) {
      int c = i * 4 + w;
      int r = c * 8 + lr;
      gl_lds16(&A[(m0 + r) * 1024 + k0 + lc], &As[c * 512]);
      gl_lds16(&Bt[(n0 + r) * 1024 + k0 + lc], &Bs[c * 512]);
    }
    __syncthreads();
#pragma unroll
    for (int kk = 0; kk < 2; ++kk) {
      s8v af[4], bf[4];
#pragma unroll
      for (int mt = 0; mt < 4; ++mt) af[mt] = *(const s8v*)&As[(wm * 64 + mt * 16 + l15) * 64 + kk * 32 + quad * 8];
#pragma unroll
      for (int nt = 0; nt < 4; ++nt) bf[nt] = *(const s8v*)&Bs[(wn * 64 + nt * 16 + l15) * 64 + kk * 32 + quad * 8];
#pragma unroll
      for (int mt = 0; mt < 4; ++mt)
#pragma unroll
        for (int nt = 0; nt < 4; ++nt)
          acc[mt][nt] = __builtin_amdgcn_mfma_f32_16x16x32_bf16(af[mt], bf[nt], acc[mt][nt], 0, 0, 0);
    }
    __syncthreads();
  }
#pragma unroll
  for (int nt = 0; nt < 4; ++nt) {
    const int col = n0 + wn * 64 + nt * 16 + l15;
    const float bcol = bias[col];
#pragma unroll
    for (int mt = 0; mt < 4; ++mt)
#pragma unroll
      for (int r = 0; r < 4; ++r) {
        const int row = m0 + wm * 64 + mt * 16 + quad * 4 + r;
        float v = (acc[mt][nt][r] + bcol) * scale;
        if (OUT_BF16) ((short*)Cout)[row * 1024 + col] = b16(v);
        else          ((float*)Cout)[row * 1024 + col] = v;
      }
  }
}

// ---------------- V transpose: Vb [b,s,h,d] -> Vt [b,h,d,s]
__global__ __launch_bounds__(256) void vtrans(const short* __restrict__ V, short* __restrict__ Vt) {
  __shared__ short T[128][72];
  const int st = blockIdx.x, h = blockIdx.y, b = blockIdx.z;
  const int tid = threadIdx.x;
#pragma unroll
  for (int i = 0; i < 4; ++i) {
    int c = tid + i * 256;
    int r = c >> 3, c8 = (c & 7) * 8;
    *(s8v*)&T[r][c8] = *(const s8v*)&V[((b * 2048 + st * 128 + r) * 16 + h) * 64 + c8];
  }
  __syncthreads();
#pragma unroll
  for (int i = 0; i < 4; ++i) {
    int id = tid + i * 256;
    int d = id & 63, s8 = id >> 6;
    s8v o;
#pragma unroll
    for (int j = 0; j < 8; ++j) o[j] = T[s8 * 8 + j][d];
    *(s8v*)&Vt[((b * 16 + h) * 64 + d) * 2048 + st * 128 + s8 * 8] = o;
  }
}

// ---------------- fused attention v6: counted-vmcnt pipeline (T3+T4).
// Per tile: vmcnt(4)+bar -> score -> lgkm+bar -> issue K(t+1), vmcnt(4) -> bar -> PV
// -> lgkm+bar -> issue V(t+1). K loads (4) always older than V loads (4), so
// vmcnt(4) drains exactly the group needed. Never vmcnt(0) in steady state.
__global__ __launch_bounds__(256, 3) void attn_ctx(const short* __restrict__ Q, const short* __restrict__ K,
                                                   const short* __restrict__ Vt,
                                                   float* __restrict__ rbuf, short* __restrict__ ctx) {
  __shared__ __align__(16) char smem[50432];
  short* Ks = (short*)smem;                 // [128 kpos][64 d]   swizzled, 16384 B
  short* Vs = (short*)(smem + 16384);       // [64 d][128 kpos]   swizzled, 16384 B
  short* Ps = (short*)(smem + 32768);       // [64 q][128 kpos]   swizzled, 16384 B
  short* Qs = Ps;                           // alias: Qs dead after frag hoist
  float* l_part = (float*)(smem + 49152);   // [4 waves][64 q]
  float* l_s    = (float*)(smem + 50176);   // [64 q] -> 1/l
  const int q64 = blockIdx.x, h = blockIdx.y, b = blockIdx.z;
  const int tid = threadIdx.x, w = tid >> 6, lane = tid & 63, quad = lane >> 4, l15 = lane & 15;
  const int bh = b * 16 + h, q0 = q64 * 64;

  // stage Q tile (64x64) swizzled (reg roundtrip; once per kernel)
#pragma unroll
  for (int i = 0; i < 2; ++i) {
    int c = tid + i * 256;
    int r = c >> 3, cc = c & 7;
    *(s8v*)&Qs[r * 64 + (((cc ^ (r & 7))) << 3)] =
        *(const s8v*)&Q[((b * 2048 + q0 + r) * 16 + h) * 64 + cc * 8];
  }
  __syncthreads();   // full drain: vmcnt=0 after this
  // hoist Q fragments (B-operand of St = K·Q^T), all 64 q cols
  s8v qf[4][2];
#pragma unroll
  for (int nt = 0; nt < 4; ++nt) {
    int r = nt * 16 + l15;
    qf[nt][0] = *(const s8v*)&Qs[r * 64 + ((quad ^ (r & 7)) << 3)];
    qf[nt][1] = *(const s8v*)&Qs[r * 64 + (((4 + quad) ^ (r & 7)) << 3)];
  }
  const short* kbase = &K[((long)(b * 2048) * 16 + h) * 64];
  const short* vbase = &Vt[(long)(bh * 64) * 2048];
  const int krow = w * 8 + (lane >> 3);
  const short* ksrc = kbase + krow * 1024 + (((lane & 7) ^ (lane >> 3)) << 3);
  const int vrow = w * 4 + (lane >> 4);
  const short* vsrc = vbase + vrow * 2048 + (((lane & 15) ^ vrow) << 3);
  f4v o[4] = {};
  float l_acc[4] = {0.f, 0.f, 0.f, 0.f};

  // prologue: issue K(0) group (4), then V(0) group (4)
#pragma unroll
  for (int i = 0; i < 4; ++i) gl_lds16(ksrc + i * 32768, &Ks[(i * 4 + w) * 512]);
#pragma unroll
  for (int i = 0; i < 4; ++i) gl_lds16(vsrc + i * 32768, &Vs[(i * 4 + w) * 512]);
  WAIT_LGKM0();   // qf reads complete before first barrier

  for (int kt = 0; kt < 16; ++kt) {
    WAIT_VM(4);                     // own K(kt) retired (V(kt) may remain)
    BAR();                          // all waves' K DMA landed
    // score phase: wave w computes St rows kpos [w*32, w*32+32), all 64 q
#pragma unroll
    for (int mt = 0; mt < 2; ++mt) {
      int kr = w * 32 + mt * 16 + l15;
      s8v a0 = *(const s8v*)&Ks[kr * 64 + ((quad ^ (kr & 7)) << 3)];
      s8v a1 = *(const s8v*)&Ks[kr * 64 + (((4 + quad) ^ (kr & 7)) << 3)];
#pragma unroll
      for (int nt = 0; nt < 4; ++nt) {
        f4v st = {};
        st = __builtin_amdgcn_mfma_f32_16x16x32_bf16(a0, qf[nt][0], st, 0, 0, 0);
        st = __builtin_amdgcn_mfma_f32_16x16x32_bf16(a1, qf[nt][1], st, 0, 0, 0);
        float e0 = fexp2(st[0]), e1 = fexp2(st[1]);
        float e2 = fexp2(st[2]), e3 = fexp2(st[3]);
        l_acc[nt] += (e0 + e1) + (e2 + e3);
        uint2 pp; pp.x = pk2(e0, e1); pp.y = pk2(e2, e3);
        int q = nt * 16 + l15;
        int chunk = (w * 4 + mt * 2 + (quad >> 1)) ^ l15;
        *(uint2*)&Ps[q * 128 + (chunk << 3) + (quad & 1) * 4] = pp;
      }
    }
    WAIT_LGKM0();                   // Ps writes + Ks reads done
    BAR();                          // Ks free, Ps visible
    if (kt < 15) {
#pragma unroll
      for (int i = 0; i < 4; ++i) gl_lds16(ksrc + (kt + 1) * 131072 + i * 32768, &Ks[(i * 4 + w) * 512]);
      WAIT_VM(4);                   // V(kt) retired (K(kt+1) outstanding)
    } else {
      WAIT_VM(0);                   // tail: only V(15) outstanding
    }
    BAR();                          // all waves' V DMA landed
    // PV phase: wave w owns q rows [w*16, w*16+16), full 128 kpos
#pragma unroll
    for (int kk = 0; kk < 4; ++kk) {
      int qr = w * 16 + l15;
      s8v a = *(const s8v*)&Ps[qr * 128 + (((kk * 4 + quad) ^ (qr & 15)) << 3)];
#pragma unroll
      for (int dt = 0; dt < 4; ++dt) {
        int d = dt * 16 + l15;
        s8v vb = *(const s8v*)&Vs[d * 128 + (((kk * 4 + quad) ^ (d & 15)) << 3)];
        o[dt] = __builtin_amdgcn_mfma_f32_16x16x32_bf16(a, vb, o[dt], 0, 0, 0);
      }
    }
    WAIT_LGKM0();                   // PV reads done
    BAR();                          // Vs, Ps free
    if (kt < 15) {
#pragma unroll
      for (int i = 0; i < 4; ++i) gl_lds16(vsrc + (kt + 1) * 128 + i * 32768, &Vs[(i * 4 + w) * 512]);
    }
  }

  // reduce l: intra-wave over quads, then cross-wave via LDS
#pragma unroll
  for (int nt = 0; nt < 4; ++nt) {
    float v = l_acc[nt];
    v += __shfl_xor(v, 16, 64);
    v += __shfl_xor(v, 32, 64);
    if (quad == 0) l_part[w * 64 + nt * 16 + l15] = v;
  }
  __syncthreads();
  if (tid < 64) {
    float s = l_part[tid] + l_part[64 + tid] + l_part[128 + tid] + l_part[192 + tid];
    float rv = 1.0f / s;
    l_s[tid] = rv;
    rbuf[bh * 2048 + q0 + tid] = rv;
  }
  __syncthreads();
  float rvq[4];
#pragma unroll
  for (int r = 0; r < 4; ++r) rvq[r] = l_s[w * 16 + quad * 4 + r];
#pragma unroll
  for (int dt = 0; dt < 4; ++dt)
#pragma unroll
    for (int r = 0; r < 4; ++r) {
      int sq = q0 + w * 16 + quad * 4 + r;
      ctx[((b * 2048 + sq) * 16 + h) * 64 + dt * 16 + l15] = b16(o[dt][r] * rvq[r]);
    }
}

// ---------------- mean over heads of probs -> [b, q, k] fp32
// v2: double-buffered Qs/Ks with counted vmcnt(8); all 16 rbuf rows preloaded once
// (keeps vmem stream pure for counting); 1/16 folded into epilogue.
__global__ __launch_bounds__(256) void mean_probs(const short* __restrict__ Q, const short* __restrict__ K,
                                                  const float* __restrict__ rbuf, float* __restrict__ outm) {
  __shared__ __align__(16) short Qs[2][8192];   // [128 q][64 d] swizzled, dbuf
  __shared__ __align__(16) short Ks[2][8192];   // [128 k][64 d] swizzled, dbuf
  __shared__ __align__(16) float r_all[2048];   // [16 h][128 q]
  const int k128 = blockIdx.x, q128 = blockIdx.y, b = blockIdx.z;
  const int tid = threadIdx.x, w = tid >> 6, lane = tid & 63, quad = lane >> 4, l15 = lane & 15;
  f4v mn[2][8] = {};
  const int mrow = w * 8 + (lane >> 3);
  const int mck8 = ((lane & 7) ^ (lane >> 3)) << 3;
  const short* qsrc = Q + ((long)(b * 2048 + q128 * 128 + mrow) * 16) * 64 + mck8;
  const short* ksrc = K + ((long)(b * 2048 + k128 * 128 + mrow) * 16) * 64 + mck8;
  // preload all 16 rows of rbuf (2 issues/wave): h = i*8 + w*2 + (lane>>5), q = (lane&31)*4
  const float* rb = rbuf + (long)(b * 16) * 2048 + q128 * 128;
#pragma unroll
  for (int i = 0; i < 2; ++i) {
    int hh = i * 8 + w * 2 + (lane >> 5);
    gl_lds16((const short*)(rb + hh * 2048 + (lane & 31) * 4), (short*)r_all + (i * 4 + w) * 512);
  }
  // issue h=0 tiles into buf0 (8 loads)
#pragma unroll
  for (int i = 0; i < 4; ++i) gl_lds16(qsrc + i * 32768, &Qs[0][(i * 4 + w) * 512]);
#pragma unroll
  for (int i = 0; i < 4; ++i) gl_lds16(ksrc + i * 32768, &Ks[0][(i * 4 + w) * 512]);

  for (int h = 0; h < 16; ++h) {
    const int cur = h & 1;
    if (h < 15) {
      // issue h+1 into other buf; overlaps with this h's compute
#pragma unroll
      for (int i = 0; i < 4; ++i) gl_lds16(qsrc + (h + 1) * 64 + i * 32768, &Qs[cur ^ 1][(i * 4 + w) * 512]);
#pragma unroll
      for (int i = 0; i < 4; ++i) gl_lds16(ksrc + (h + 1) * 64 + i * 32768, &Ks[cur ^ 1][(i * 4 + w) * 512]);
      WAIT_VM(8);   // drains h's 8 (+ r_all's 2 at h=0); h+1's 8 stay in flight
    } else {
      WAIT_VM(0);
    }
    BAR();          // all waves' DMA for h landed
    s8v aq[2][2];
#pragma unroll
    for (int qt = 0; qt < 2; ++qt) {
      int r = w * 32 + qt * 16 + l15;
      aq[qt][0] = *(const s8v*)&Qs[cur][r * 64 + ((quad ^ (r & 7)) << 3)];
      aq[qt][1] = *(const s8v*)&Qs[cur][r * 64 + (((4 + quad) ^ (r & 7)) << 3)];
    }
    float rr[2][4];
#pragma unroll
    for (int qt = 0; qt < 2; ++qt)
#pragma unroll
      for (int r = 0; r < 4; ++r) rr[qt][r] = r_all[h * 128 + w * 32 + qt * 16 + quad * 4 + r];
#pragma unroll
    for (int ktile = 0; ktile < 8; ++ktile) {
      int kr = ktile * 16 + l15;
      s8v b0 = *(const s8v*)&Ks[cur][kr * 64 + ((quad ^ (kr & 7)) << 3)];
      s8v b1 = *(const s8v*)&Ks[cur][kr * 64 + (((4 + quad) ^ (kr & 7)) << 3)];
#pragma unroll
      for (int qt = 0; qt < 2; ++qt) {
        f4v sc = {};
        sc = __builtin_amdgcn_mfma_f32_16x16x32_bf16(aq[qt][0], b0, sc, 0, 0, 0);
        sc = __builtin_amdgcn_mfma_f32_16x16x32_bf16(aq[qt][1], b1, sc, 0, 0, 0);
#pragma unroll
        for (int r = 0; r < 4; ++r)
          mn[qt][ktile][r] += fexp2(sc[r]) * rr[qt][r];
      }
    }
    WAIT_LGKM0();   // this buf's reads done
    BAR();          // buf free for h+2's DMA
  }
#pragma unroll
  for (int qt = 0; qt < 2; ++qt)
#pragma unroll
    for (int ktile = 0; ktile < 8; ++ktile)
#pragma unroll
      for (int r = 0; r < 4; ++r) {
        long qrow = q128 * 128 + w * 32 + qt * 16 + quad * 4 + r;
        outm[((long)b * 2048 + qrow) * 2048 + k128 * 128 + ktile * 16 + l15] = mn[qt][ktile][r] * 0.0625f;
      }
}

extern "C" void kernel_launch(void* const* d_in, const int* in_sizes, int n_in,
                              void* d_out, int out_size, void* d_ws, size_t ws_size,
                              hipStream_t stream) {
  (void)in_sizes; (void)n_in; (void)out_size; (void)ws_size;
  const float* x  = (const float*)d_in[0];
  const float* Wq = (const float*)d_in[1];
  const float* bq = (const float*)d_in[2];
  const float* Wk = (const float*)d_in[3];
  const float* bk = (const float*)d_in[4];
  const float* Wv = (const float*)d_in[5];
  const float* bv = (const float*)d_in[6];
  const float* Wo = (const float*)d_in[7];
  const float* bo = (const float*)d_in[8];
  float* out  = (float*)d_out;
  float* outm = out + 8388608;

  char* ws = (char*)d_ws;
  short* xb  = (short*)(ws);                 // 16 MB (reused as ctx)
  short* Wqt = (short*)(ws + 16777216);
  short* Wkt = (short*)(ws + 18874368);
  short* Wvt = (short*)(ws + 20971520);
  short* Wot = (short*)(ws + 23068672);
  short* Qb  = (short*)(ws + 25165824);      // 16 MB
  short* Kb  = (short*)(ws + 41943040);      // 16 MB
  short* Vb  = (short*)(ws + 58720256);      // 16 MB (dead after vtrans)
  short* Vt  = (short*)(ws + 75497472);      // 16 MB
  float* rbuf = (float*)Vb;                  // 512 KB alias in dead Vb
  short* ctx = xb;                           // alias: xb dead after QKV GEMMs

  const float C2 = 0.18033688011112042f;     // (1/8) * log2(e), folded into Q projection

  cast_f32_bf16<<<8192, 256, 0, stream>>>(x, xb, 2097152);
  wtrans<<<512, 256, 0, stream>>>(Wq, Wqt);
  wtrans<<<512, 256, 0, stream>>>(Wk, Wkt);
  wtrans<<<512, 256, 0, stream>>>(Wv, Wvt);
  wtrans<<<512, 256, 0, stream>>>(Wo, Wot);
  dim3 gg(8, 64);
  gemm128<true><<<gg, 256, 0, stream>>>(xb, Wqt, bq, Qb, C2);     // Q pre-scaled
  gemm128<true><<<gg, 256, 0, stream>>>(xb, Wkt, bk, Kb, 1.0f);
  gemm128<true><<<gg, 256, 0, stream>>>(xb, Wvt, bv, Vb, 1.0f);
  vtrans<<<dim3(16, 16, 4), 256, 0, stream>>>(Vb, Vt);
  attn_ctx<<<dim3(32, 16, 4), 256, 0, stream>>>(Qb, Kb, Vt, rbuf, ctx);
  mean_probs<<<dim3(16, 16, 4), 256, 0, stream>>>(Qb, Kb, rbuf, outm);
  gemm128<false><<<gg, 256, 0, stream>>>(ctx, Wot, bo, out, 1.0f);
}

// Round 4
// 432.967 us; speedup vs baseline: 1.0671x; 1.0134x over previous
//
#include <hip/hip_runtime.h>

typedef __attribute__((ext_vector_type(8))) short s8v;
typedef __attribute__((ext_vector_type(4))) short s4v;
typedef __attribute__((ext_vector_type(4))) float f4v;

#define DEV __device__ __forceinline__

DEV short b16(float f) {
  unsigned u = __builtin_bit_cast(unsigned, f);
  u = (u + 0x7fffu + ((u >> 16) & 1u)) >> 16;
  return (short)u;
}

// packed f32x2 -> bf16x2 (RNE) as one uint
DEV unsigned pk2(float a, float b) {
#if __has_builtin(__builtin_amdgcn_cvt_pk_bf16_f32)
  auto p = __builtin_amdgcn_cvt_pk_bf16_f32(a, b);
  return __builtin_bit_cast(unsigned, p);
#else
  return (unsigned)(unsigned short)b16(a) | ((unsigned)(unsigned short)b16(b) << 16);
#endif
}

DEV float fexp2(float x) {
#if __has_builtin(__builtin_amdgcn_exp2f)
  return __builtin_amdgcn_exp2f(x);
#else
  return exp2f(x);
#endif
}

// async global->LDS, 16B per lane; lds base must be wave-uniform
DEV void gl_lds16(const short* g, short* l) {
  __builtin_amdgcn_global_load_lds((const __attribute__((address_space(1))) void*)g,
                                   (__attribute__((address_space(3))) void*)l, 16, 0, 0);
}

#define WAIT_VM(N) asm volatile("s_waitcnt vmcnt(" #N ")" ::: "memory")
#define WAIT_LGKM0() asm volatile("s_waitcnt lgkmcnt(0)" ::: "memory")
#define BAR() __builtin_amdgcn_s_barrier()

// ---------------- cast x: fp32 -> bf16
__global__ __launch_bounds__(256) void cast_f32_bf16(const float* __restrict__ in,
                                                     short* __restrict__ out, int n4) {
  int i = blockIdx.x * 256 + threadIdx.x;
  if (i >= n4) return;
  float4 v = ((const float4*)in)[i];
  s4v o; o.x = b16(v.x); o.y = b16(v.y); o.z = b16(v.z); o.w = b16(v.w);
  ((s4v*)out)[i] = o;
}

// ---------------- transpose-cast W [1024 k][1024 n] fp32 -> Wt [n][k] bf16
__global__ __launch_bounds__(256) void wtrans(const float* __restrict__ W, short* __restrict__ Wt) {
  int id = blockIdx.x * 256 + threadIdx.x;
  int k8 = id >> 10;
  int n  = id & 1023;
  s8v o;
#pragma unroll
  for (int j = 0; j < 8; ++j) o[j] = b16(W[(k8 * 8 + j) * 1024 + n]);
  *(s8v*)&Wt[n * 1024 + k8 * 8] = o;
}

// ---------------- GEMM: C[8192x1024] = (A(bf16) x Bt^T + bias) * scale; global_load_lds staging
template <bool OUT_BF16>
__global__ __launch_bounds__(256) void gemm128(const short* __restrict__ A,
                                               const short* __restrict__ Bt,
                                               const float* __restrict__ bias,
                                               void* __restrict__ Cout, float scale) {
  __shared__ short As[128 * 64];
  __shared__ short Bs[128 * 64];
  const int tid = threadIdx.x;
  const int w = tid >> 6, lane = tid & 63, quad = lane >> 4, l15 = lane & 15;
  const int wm = w >> 1, wn = w & 1;
  const int m0 = blockIdx.y * 128, n0 = blockIdx.x * 128;
  const int lr = lane >> 3, lc = (lane & 7) * 8;
  f4v acc[4][4] = {};
  for (int k0 = 0; k0 < 1024; k0 += 64) {
#pragma unroll
    for (int i = 0; i < 4; ++i) {
      int c = i * 4 + w;
      int r = c * 8 + lr;
      gl_lds16(&A[(m0 + r) * 1024 + k0 + lc], &As[c * 512]);
      gl_lds16(&Bt[(n0 + r) * 1024 + k0 + lc], &Bs[c * 512]);
    }
    __syncthreads();
#pragma unroll
    for (int kk = 0; kk < 2; ++kk) {
      s8v af[4], bf[4];
#pragma unroll
      for (int mt = 0; mt < 4; ++mt) af[mt] = *(const s8v*)&As[(wm * 64 + mt * 16 + l15) * 64 + kk * 32 + quad * 8];
#pragma unroll
      for (int nt = 0; nt < 4; ++nt) bf[nt] = *(const s8v*)&Bs[(wn * 64 + nt * 16 + l15) * 64 + kk * 32 + quad * 8];
#pragma unroll
      for (int mt = 0; mt < 4; ++mt)
#pragma unroll
        for (int nt = 0; nt < 4; ++nt)
          acc[mt][nt] = __builtin_amdgcn_mfma_f32_16x16x32_bf16(af[mt], bf[nt], acc[mt][nt], 0, 0, 0);
    }
    __syncthreads();
  }
#pragma unroll
  for (int nt = 0; nt < 4; ++nt) {
    const int col = n0 + wn * 64 + nt * 16 + l15;
    const float bcol = bias[col];
#pragma unroll
    for (int mt = 0; mt < 4; ++mt)
#pragma unroll
      for (int r = 0; r < 4; ++r) {
        const int row = m0 + wm * 64 + mt * 16 + quad * 4 + r;
        float v = (acc[mt][nt][r] + bcol) * scale;
        if (OUT_BF16) ((short*)Cout)[row * 1024 + col] = b16(v);
        else          ((float*)Cout)[row * 1024 + col] = v;
      }
  }
}

// ---------------- V transpose: Vb [b,s,h,d] -> Vt [b,h,d,s]
__global__ __launch_bounds__(256) void vtrans(const short* __restrict__ V, short* __restrict__ Vt) {
  __shared__ short T[128][72];
  const int st = blockIdx.x, h = blockIdx.y, b = blockIdx.z;
  const int tid = threadIdx.x;
#pragma unroll
  for (int i = 0; i < 4; ++i) {
    int c = tid + i * 256;
    int r = c >> 3, c8 = (c & 7) * 8;
    *(s8v*)&T[r][c8] = *(const s8v*)&V[((b * 2048 + st * 128 + r) * 16 + h) * 64 + c8];
  }
  __syncthreads();
#pragma unroll
  for (int i = 0; i < 4; ++i) {
    int id = tid + i * 256;
    int d = id & 63, s8 = id >> 6;
    s8v o;
#pragma unroll
    for (int j = 0; j < 8; ++j) o[j] = T[s8 * 8 + j][d];
    *(s8v*)&Vt[((b * 16 + h) * 64 + d) * 2048 + st * 128 + s8 * 8] = o;
  }
}

// ---------------- fused attention v7: counted-vmcnt pipeline + l-via-MFMA.
// l[q] = sum_k P[q][k] computed by one extra MFMA per kk with all-ones B operand
// (reuses the PV A-fragment). Result lands in the SAME lane layout as o[dt]
// (q = w*16 + quad*4 + r), so the cross-wave l reduce disappears entirely.
__global__ __launch_bounds__(256, 3) void attn_ctx(const short* __restrict__ Q, const short* __restrict__ K,
                                                   const short* __restrict__ Vt,
                                                   float* __restrict__ rbuf, short* __restrict__ ctx) {
  __shared__ __align__(16) char smem[49152];
  short* Ks = (short*)smem;                 // [128 kpos][64 d]   swizzled, 16384 B
  short* Vs = (short*)(smem + 16384);       // [64 d][128 kpos]   swizzled, 16384 B
  short* Ps = (short*)(smem + 32768);       // [64 q][128 kpos]   swizzled, 16384 B
  short* Qs = Ps;                           // alias: Qs dead after frag hoist
  const int q64 = blockIdx.x, h = blockIdx.y, b = blockIdx.z;
  const int tid = threadIdx.x, w = tid >> 6, lane = tid & 63, quad = lane >> 4, l15 = lane & 15;
  const int bh = b * 16 + h, q0 = q64 * 64;

  // stage Q tile (64x64) swizzled (reg roundtrip; once per kernel)
#pragma unroll
  for (int i = 0; i < 2; ++i) {
    int c = tid + i * 256;
    int r = c >> 3, cc = c & 7;
    *(s8v*)&Qs[r * 64 + (((cc ^ (r & 7))) << 3)] =
        *(const s8v*)&Q[((b * 2048 + q0 + r) * 16 + h) * 64 + cc * 8];
  }
  __syncthreads();   // full drain: vmcnt=0 after this
  // hoist Q fragments (B-operand of St = K·Q^T), all 64 q cols
  s8v qf[4][2];
#pragma unroll
  for (int nt = 0; nt < 4; ++nt) {
    int r = nt * 16 + l15;
    qf[nt][0] = *(const s8v*)&Qs[r * 64 + ((quad ^ (r & 7)) << 3)];
    qf[nt][1] = *(const s8v*)&Qs[r * 64 + (((4 + quad) ^ (r & 7)) << 3)];
  }
  const short* kbase = &K[((long)(b * 2048) * 16 + h) * 64];
  const short* vbase = &Vt[(long)(bh * 64) * 2048];
  const int krow = w * 8 + (lane >> 3);
  const short* ksrc = kbase + krow * 1024 + (((lane & 7) ^ (lane >> 3)) << 3);
  const int vrow = w * 4 + (lane >> 4);
  const short* vsrc = vbase + vrow * 2048 + (((lane & 15) ^ vrow) << 3);
  f4v o[4] = {};
  f4v lf = {};
  s8v ones;
#pragma unroll
  for (int j = 0; j < 8; ++j) ones[j] = (short)0x3F80;   // bf16 1.0

  // prologue: issue K(0) group (4), then V(0) group (4)
#pragma unroll
  for (int i = 0; i < 4; ++i) gl_lds16(ksrc + i * 32768, &Ks[(i * 4 + w) * 512]);
#pragma unroll
  for (int i = 0; i < 4; ++i) gl_lds16(vsrc + i * 32768, &Vs[(i * 4 + w) * 512]);
  WAIT_LGKM0();   // qf reads complete before first barrier

  for (int kt = 0; kt < 16; ++kt) {
    WAIT_VM(4);                     // own K(kt) retired (V(kt) may remain)
    BAR();                          // all waves' K DMA landed
    // score phase: wave w computes St rows kpos [w*32, w*32+32), all 64 q
#pragma unroll
    for (int mt = 0; mt < 2; ++mt) {
      int kr = w * 32 + mt * 16 + l15;
      s8v a0 = *(const s8v*)&Ks[kr * 64 + ((quad ^ (kr & 7)) << 3)];
      s8v a1 = *(const s8v*)&Ks[kr * 64 + (((4 + quad) ^ (kr & 7)) << 3)];
#pragma unroll
      for (int nt = 0; nt < 4; ++nt) {
        f4v st = {};
        st = __builtin_amdgcn_mfma_f32_16x16x32_bf16(a0, qf[nt][0], st, 0, 0, 0);
        st = __builtin_amdgcn_mfma_f32_16x16x32_bf16(a1, qf[nt][1], st, 0, 0, 0);
        float e0 = fexp2(st[0]), e1 = fexp2(st[1]);
        float e2 = fexp2(st[2]), e3 = fexp2(st[3]);
        uint2 pp; pp.x = pk2(e0, e1); pp.y = pk2(e2, e3);
        int q = nt * 16 + l15;
        int chunk = (w * 4 + mt * 2 + (quad >> 1)) ^ l15;
        *(uint2*)&Ps[q * 128 + (chunk << 3) + (quad & 1) * 4] = pp;
      }
    }
    WAIT_LGKM0();                   // Ps writes + Ks reads done
    BAR();                          // Ks free, Ps visible
    if (kt < 15) {
#pragma unroll
      for (int i = 0; i < 4; ++i) gl_lds16(ksrc + (kt + 1) * 131072 + i * 32768, &Ks[(i * 4 + w) * 512]);
      WAIT_VM(4);                   // V(kt) retired (K(kt+1) outstanding)
    } else {
      WAIT_VM(0);                   // tail: only V(15) outstanding
    }
    BAR();                          // all waves' V DMA landed
    // PV phase: wave w owns q rows [w*16, w*16+16), full 128 kpos
#pragma unroll
    for (int kk = 0; kk < 4; ++kk) {
      int qr = w * 16 + l15;
      s8v a = *(const s8v*)&Ps[qr * 128 + (((kk * 4 + quad) ^ (qr & 15)) << 3)];
#pragma unroll
      for (int dt = 0; dt < 4; ++dt) {
        int d = dt * 16 + l15;
        s8v vb = *(const s8v*)&Vs[d * 128 + (((kk * 4 + quad) ^ (d & 15)) << 3)];
        o[dt] = __builtin_amdgcn_mfma_f32_16x16x32_bf16(a, vb, o[dt], 0, 0, 0);
      }
      lf = __builtin_amdgcn_mfma_f32_16x16x32_bf16(a, ones, lf, 0, 0, 0);
    }
    WAIT_LGKM0();                   // PV reads done
    BAR();                          // Vs, Ps free
    if (kt < 15) {
#pragma unroll
      for (int i = 0; i < 4; ++i) gl_lds16(vsrc + (kt + 1) * 128 + i * 32768, &Vs[(i * 4 + w) * 512]);
    }
  }

  // lf[r] = l for q = w*16 + quad*4 + r (replicated across l15). No reduce needed.
  float rv[4];
#pragma unroll
  for (int r = 0; r < 4; ++r) rv[r] = 1.0f / lf[r];
  if (l15 == 0) {
    f4v t; t[0] = rv[0]; t[1] = rv[1]; t[2] = rv[2]; t[3] = rv[3];
    *(f4v*)&rbuf[bh * 2048 + q0 + w * 16 + quad * 4] = t;
  }
#pragma unroll
  for (int dt = 0; dt < 4; ++dt)
#pragma unroll
    for (int r = 0; r < 4; ++r) {
      int sq = q0 + w * 16 + quad * 4 + r;
      ctx[((b * 2048 + sq) * 16 + h) * 64 + dt * 16 + l15] = b16(o[dt][r] * rv[r]);
    }
}

// ---------------- mean over heads of probs -> [b, q, k] fp32
// double-buffered Qs/Ks with counted vmcnt(8); all 16 rbuf rows preloaded once
// (keeps vmem stream pure for counting); 1/16 folded into epilogue.
__global__ __launch_bounds__(256) void mean_probs(const short* __restrict__ Q, const short* __restrict__ K,
                                                  const float* __restrict__ rbuf, float* __restrict__ outm) {
  __shared__ __align__(16) short Qs[2][8192];   // [128 q][64 d] swizzled, dbuf
  __shared__ __align__(16) short Ks[2][8192];   // [128 k][64 d] swizzled, dbuf
  __shared__ __align__(16) float r_all[2048];   // [16 h][128 q]
  const int k128 = blockIdx.x, q128 = blockIdx.y, b = blockIdx.z;
  const int tid = threadIdx.x, w = tid >> 6, lane = tid & 63, quad = lane >> 4, l15 = lane & 15;
  f4v mn[2][8] = {};
  const int mrow = w * 8 + (lane >> 3);
  const int mck8 = ((lane & 7) ^ (lane >> 3)) << 3;
  const short* qsrc = Q + ((long)(b * 2048 + q128 * 128 + mrow) * 16) * 64 + mck8;
  const short* ksrc = K + ((long)(b * 2048 + k128 * 128 + mrow) * 16) * 64 + mck8;
  // preload all 16 rows of rbuf (2 issues/wave): h = i*8 + w*2 + (lane>>5), q = (lane&31)*4
  const float* rb = rbuf + (long)(b * 16) * 2048 + q128 * 128;
#pragma unroll
  for (int i = 0; i < 2; ++i) {
    int hh = i * 8 + w * 2 + (lane >> 5);
    gl_lds16((const short*)(rb + hh * 2048 + (lane & 31) * 4), (short*)r_all + (i * 4 + w) * 512);
  }
  // issue h=0 tiles into buf0 (8 loads)
#pragma unroll
  for (int i = 0; i < 4; ++i) gl_lds16(qsrc + i * 32768, &Qs[0][(i * 4 + w) * 512]);
#pragma unroll
  for (int i = 0; i < 4; ++i) gl_lds16(ksrc + i * 32768, &Ks[0][(i * 4 + w) * 512]);

  for (int h = 0; h < 16; ++h) {
    const int cur = h & 1;
    if (h < 15) {
      // issue h+1 into other buf; overlaps with this h's compute
#pragma unroll
      for (int i = 0; i < 4; ++i) gl_lds16(qsrc + (h + 1) * 64 + i * 32768, &Qs[cur ^ 1][(i * 4 + w) * 512]);
#pragma unroll
      for (int i = 0; i < 4; ++i) gl_lds16(ksrc + (h + 1) * 64 + i * 32768, &Ks[cur ^ 1][(i * 4 + w) * 512]);
      WAIT_VM(8);   // drains h's 8 (+ r_all's 2 at h=0); h+1's 8 stay in flight
    } else {
      WAIT_VM(0);
    }
    BAR();          // all waves' DMA for h landed
    s8v aq[2][2];
#pragma unroll
    for (int qt = 0; qt < 2; ++qt) {
      int r = w * 32 + qt * 16 + l15;
      aq[qt][0] = *(const s8v*)&Qs[cur][r * 64 + ((quad ^ (r & 7)) << 3)];
      aq[qt][1] = *(const s8v*)&Qs[cur][r * 64 + (((4 + quad) ^ (r & 7)) << 3)];
    }
    float rr[2][4];
#pragma unroll
    for (int qt = 0; qt < 2; ++qt)
#pragma unroll
      for (int r = 0; r < 4; ++r) rr[qt][r] = r_all[h * 128 + w * 32 + qt * 16 + quad * 4 + r];
#pragma unroll
    for (int ktile = 0; ktile < 8; ++ktile) {
      int kr = ktile * 16 + l15;
      s8v b0 = *(const s8v*)&Ks[cur][kr * 64 + ((quad ^ (kr & 7)) << 3)];
      s8v b1 = *(const s8v*)&Ks[cur][kr * 64 + (((4 + quad) ^ (kr & 7)) << 3)];
#pragma unroll
      for (int qt = 0; qt < 2; ++qt) {
        f4v sc = {};
        sc = __builtin_amdgcn_mfma_f32_16x16x32_bf16(aq[qt][0], b0, sc, 0, 0, 0);
        sc = __builtin_amdgcn_mfma_f32_16x16x32_bf16(aq[qt][1], b1, sc, 0, 0, 0);
#pragma unroll
        for (int r = 0; r < 4; ++r)
          mn[qt][ktile][r] += fexp2(sc[r]) * rr[qt][r];
      }
    }
    WAIT_LGKM0();   // this buf's reads done
    BAR();          // buf free for h+2's DMA
  }
#pragma unroll
  for (int qt = 0; qt < 2; ++qt)
#pragma unroll
    for (int ktile = 0; ktile < 8; ++ktile)
#pragma unroll
      for (int r = 0; r < 4; ++r) {
        long qrow = q128 * 128 + w * 32 + qt * 16 + quad * 4 + r;
        outm[((long)b * 2048 + qrow) * 2048 + k128 * 128 + ktile * 16 + l15] = mn[qt][ktile][r] * 0.0625f;
      }
}

extern "C" void kernel_launch(void* const* d_in, const int* in_sizes, int n_in,
                              void* d_out, int out_size, void* d_ws, size_t ws_size,
                              hipStream_t stream) {
  (void)in_sizes; (void)n_in; (void)out_size; (void)ws_size;
  const float* x  = (const float*)d_in[0];
  const float* Wq = (const float*)d_in[1];
  const float* bq = (const float*)d_in[2];
  const float* Wk = (const float*)d_in[3];
  const float* bk = (const float*)d_in[4];
  const float* Wv = (const float*)d_in[5];
  const float* bv = (const float*)d_in[6];
  const float* Wo = (const float*)d_in[7];
  const float* bo = (const float*)d_in[8];
  float* out  = (float*)d_out;
  float* outm = out + 8388608;

  char* ws = (char*)d_ws;
  short* xb  = (short*)(ws);                 // 16 MB (reused as ctx)
  short* Wqt = (short*)(ws + 16777216);
  short* Wkt = (short*)(ws + 18874368);
  short* Wvt = (short*)(ws + 20971520);
  short* Wot = (short*)(ws + 23068672);
  short* Qb  = (short*)(ws + 25165824);      // 16 MB
  short* Kb  = (short*)(ws + 41943040);      // 16 MB
  short* Vb  = (short*)(ws + 58720256);      // 16 MB (dead after vtrans)
  short* Vt  = (short*)(ws + 75497472);      // 16 MB
  float* rbuf = (float*)Vb;                  // 512 KB alias in dead Vb
  short* ctx = xb;                           // alias: xb dead after QKV GEMMs

  const float C2 = 0.18033688011112042f;     // (1/8) * log2(e), folded into Q projection

  cast_f32_bf16<<<8192, 256, 0, stream>>>(x, xb, 2097152);
  wtrans<<<512, 256, 0, stream>>>(Wq, Wqt);
  wtrans<<<512, 256, 0, stream>>>(Wk, Wkt);
  wtrans<<<512, 256, 0, stream>>>(Wv, Wvt);
  wtrans<<<512, 256, 0, stream>>>(Wo, Wot);
  dim3 gg(8, 64);
  gemm128<true><<<gg, 256, 0, stream>>>(xb, Wqt, bq, Qb, C2);     // Q pre-scaled
  gemm128<true><<<gg, 256, 0, stream>>>(xb, Wkt, bk, Kb, 1.0f);
  gemm128<true><<<gg, 256, 0, stream>>>(xb, Wvt, bv, Vb, 1.0f);
  vtrans<<<dim3(16, 16, 4), 256, 0, stream>>>(Vb, Vt);
  attn_ctx<<<dim3(32, 16, 4), 256, 0, stream>>>(Qb, Kb, Vt, rbuf, ctx);
  mean_probs<<<dim3(16, 16, 4), 256, 0, stream>>>(Qb, Kb, rbuf, outm);
  gemm128<false><<<gg, 256, 0, stream>>>(ctx, Wot, bo, out, 1.0f);
}

// Round 5
// 413.169 us; speedup vs baseline: 1.1182x; 1.0479x over previous
//
#include <hip/hip_runtime.h>

typedef __attribute__((ext_vector_type(8))) short s8v;
typedef __attribute__((ext_vector_type(4))) short s4v;
typedef __attribute__((ext_vector_type(4))) float f4v;

#define DEV __device__ __forceinline__

DEV short b16(float f) {
  unsigned u = __builtin_bit_cast(unsigned, f);
  u = (u + 0x7fffu + ((u >> 16) & 1u)) >> 16;
  return (short)u;
}

// packed f32x2 -> bf16x2 (RNE) as one uint
DEV unsigned pk2(float a, float b) {
#if __has_builtin(__builtin_amdgcn_cvt_pk_bf16_f32)
  auto p = __builtin_amdgcn_cvt_pk_bf16_f32(a, b);
  return __builtin_bit_cast(unsigned, p);
#else
  return (unsigned)(unsigned short)b16(a) | ((unsigned)(unsigned short)b16(b) << 16);
#endif
}

DEV float fexp2(float x) {
#if __has_builtin(__builtin_amdgcn_exp2f)
  return __builtin_amdgcn_exp2f(x);
#else
  return exp2f(x);
#endif
}

// async global->LDS, 16B per lane; lds base must be wave-uniform
DEV void gl_lds16(const short* g, short* l) {
  __builtin_amdgcn_global_load_lds((const __attribute__((address_space(1))) void*)g,
                                   (__attribute__((address_space(3))) void*)l, 16, 0, 0);
}

#define WAIT_VM(N) asm volatile("s_waitcnt vmcnt(" #N ")" ::: "memory")
#define WAIT_LGKM0() asm volatile("s_waitcnt lgkmcnt(0)" ::: "memory")
#define BAR() __builtin_amdgcn_s_barrier()

// ---------------- cast x: fp32 -> bf16
__global__ __launch_bounds__(256) void cast_f32_bf16(const float* __restrict__ in,
                                                     short* __restrict__ out, int n4) {
  int i = blockIdx.x * 256 + threadIdx.x;
  if (i >= n4) return;
  float4 v = ((const float4*)in)[i];
  s4v o; o.x = b16(v.x); o.y = b16(v.y); o.z = b16(v.z); o.w = b16(v.w);
  ((s4v*)out)[i] = o;
}

// ---------------- transpose-cast 4x W [1024 k][1024 n] fp32 -> Wt [n][k] bf16 (contiguous outs)
__global__ __launch_bounds__(256) void wtrans4(const float* __restrict__ W0, const float* __restrict__ W1,
                                               const float* __restrict__ W2, const float* __restrict__ W3,
                                               short* __restrict__ Wt) {
  const int mat = blockIdx.y;
  const float* W = mat == 0 ? W0 : (mat == 1 ? W1 : (mat == 2 ? W2 : W3));
  short* out = Wt + (long)mat * 1048576;
  int id = blockIdx.x * 256 + threadIdx.x;
  int k8 = id >> 10;
  int n  = id & 1023;
  s8v o;
#pragma unroll
  for (int j = 0; j < 8; ++j) o[j] = b16(W[(k8 * 8 + j) * 1024 + n]);
  *(s8v*)&out[n * 1024 + k8 * 8] = o;
}

// ---------------- fused QKV GEMM: C[8192x3072] = (A(bf16) x [Wq|Wk|Wv]^T + bias) * scale
// Wt buffers contiguous (Wqt+mat*1M shorts); outputs contiguous (Qb+mat*8M shorts).
// XCD-chunked swizzle: 24 n-blocks sharing an A-tile co-reside on one XCD.
__global__ __launch_bounds__(256) void gemm_qkv(const short* __restrict__ A,
                                                const short* __restrict__ Wt,
                                                const float* __restrict__ bq,
                                                const float* __restrict__ bk,
                                                const float* __restrict__ bv,
                                                short* __restrict__ Cb, float qscale) {
  __shared__ short As[128 * 64];
  __shared__ short Bs[128 * 64];
  int n = blockIdx.x + 24 * blockIdx.y;          // 0..1535
  int id = (n & 7) * 192 + (n >> 3);             // bijective (1536 % 8 == 0)
  const int nx = id % 24, my = id / 24;
  const int mat = nx >> 3;
  const short* Bt = Wt + (long)mat * 1048576;
  const float* bias = mat == 0 ? bq : (mat == 1 ? bk : bv);
  short* Cout = Cb + (long)mat * 8388608;
  const float scale = mat == 0 ? qscale : 1.0f;
  const int m0 = my * 128, n0 = (nx & 7) * 128;
  const int tid = threadIdx.x;
  const int w = tid >> 6, lane = tid & 63, quad = lane >> 4, l15 = lane & 15;
  const int wm = w >> 1, wn = w & 1;
  const int lr = lane >> 3, lc = (lane & 7) * 8;
  f4v acc[4][4] = {};
  for (int k0 = 0; k0 < 1024; k0 += 64) {
#pragma unroll
    for (int i = 0; i < 4; ++i) {
      int c = i * 4 + w;
      int r = c * 8 + lr;
      gl_lds16(&A[(m0 + r) * 1024 + k0 + lc], &As[c * 512]);
      gl_lds16(&Bt[(n0 + r) * 1024 + k0 + lc], &Bs[c * 512]);
    }
    __syncthreads();
#pragma unroll
    for (int kk = 0; kk < 2; ++kk) {
      s8v af[4], bf[4];
#pragma unroll
      for (int mt = 0; mt < 4; ++mt) af[mt] = *(const s8v*)&As[(wm * 64 + mt * 16 + l15) * 64 + kk * 32 + quad * 8];
#pragma unroll
      for (int nt = 0; nt < 4; ++nt) bf[nt] = *(const s8v*)&Bs[(wn * 64 + nt * 16 + l15) * 64 + kk * 32 + quad * 8];
#pragma unroll
      for (int mt = 0; mt < 4; ++mt)
#pragma unroll
        for (int nt = 0; nt < 4; ++nt)
          acc[mt][nt] = __builtin_amdgcn_mfma_f32_16x16x32_bf16(af[mt], bf[nt], acc[mt][nt], 0, 0, 0);
    }
    __syncthreads();
  }
#pragma unroll
  for (int nt = 0; nt < 4; ++nt) {
    const int col = n0 + wn * 64 + nt * 16 + l15;
    const float bcol = bias[col];
#pragma unroll
    for (int mt = 0; mt < 4; ++mt)
#pragma unroll
      for (int r = 0; r < 4; ++r) {
        const int row = m0 + wm * 64 + mt * 16 + quad * 4 + r;
        Cout[row * 1024 + col] = b16((acc[mt][nt][r] + bcol) * scale);
      }
  }
}

// ---------------- GEMM (Wo): C[8192x1024] = A(bf16) x Bt^T + bias, fp32 out; XCD swizzle
__global__ __launch_bounds__(256) void gemm128(const short* __restrict__ A,
                                               const short* __restrict__ Bt,
                                               const float* __restrict__ bias,
                                               float* __restrict__ Cout) {
  __shared__ short As[128 * 64];
  __shared__ short Bs[128 * 64];
  int n = blockIdx.x + 8 * blockIdx.y;           // 0..511
  int id = (n & 7) * 64 + (n >> 3);              // bijective (512 % 8 == 0)
  const int m0 = (id >> 3) * 128, n0 = (id & 7) * 128;
  const int tid = threadIdx.x;
  const int w = tid >> 6, lane = tid & 63, quad = lane >> 4, l15 = lane & 15;
  const int wm = w >> 1, wn = w & 1;
  const int lr = lane >> 3, lc = (lane & 7) * 8;
  f4v acc[4][4] = {};
  for (int k0 = 0; k0 < 1024; k0 += 64) {
#pragma unroll
    for (int i = 0; i < 4; ++i) {
      int c = i * 4 + w;
      int r = c * 8 + lr;
      gl_lds16(&A[(m0 + r) * 1024 + k0 + lc], &As[c * 512]);
      gl_lds16(&Bt[(n0 + r) * 1024 + k0 + lc], &Bs[c * 512]);
    }
    __syncthreads();
#pragma unroll
    for (int kk = 0; kk < 2; ++kk) {
      s8v af[4], bf[4];
#pragma unroll
      for (int mt = 0; mt < 4; ++mt) af[mt] = *(const s8v*)&As[(wm * 64 + mt * 16 + l15) * 64 + kk * 32 + quad * 8];
#pragma unroll
      for (int nt = 0; nt < 4; ++nt) bf[nt] = *(const s8v*)&Bs[(wn * 64 + nt * 16 + l15) * 64 + kk * 32 + quad * 8];
#pragma unroll
      for (int mt = 0; mt < 4; ++mt)
#pragma unroll
        for (int nt = 0; nt < 4; ++nt)
          acc[mt][nt] = __builtin_amdgcn_mfma_f32_16x16x32_bf16(af[mt], bf[nt], acc[mt][nt], 0, 0, 0);
    }
    __syncthreads();
  }
#pragma unroll
  for (int nt = 0; nt < 4; ++nt) {
    const int col = n0 + wn * 64 + nt * 16 + l15;
    const float bcol = bias[col];
#pragma unroll
    for (int mt = 0; mt < 4; ++mt)
#pragma unroll
      for (int r = 0; r < 4; ++r) {
        const int row = m0 + wm * 64 + mt * 16 + quad * 4 + r;
        Cout[row * 1024 + col] = acc[mt][nt][r] + bcol;
      }
  }
}

// ---------------- V transpose: Vb [b,s,h,d] -> Vt [b,h,d,s]
__global__ __launch_bounds__(256) void vtrans(const short* __restrict__ V, short* __restrict__ Vt) {
  __shared__ short T[128][72];
  const int st = blockIdx.x, h = blockIdx.y, b = blockIdx.z;
  const int tid = threadIdx.x;
#pragma unroll
  for (int i = 0; i < 4; ++i) {
    int c = tid + i * 256;
    int r = c >> 3, c8 = (c & 7) * 8;
    *(s8v*)&T[r][c8] = *(const s8v*)&V[((b * 2048 + st * 128 + r) * 16 + h) * 64 + c8];
  }
  __syncthreads();
#pragma unroll
  for (int i = 0; i < 4; ++i) {
    int id = tid + i * 256;
    int d = id & 63, s8 = id >> 6;
    s8v o;
#pragma unroll
    for (int j = 0; j < 8; ++j) o[j] = T[s8 * 8 + j][d];
    *(s8v*)&Vt[((b * 16 + h) * 64 + d) * 2048 + st * 128 + s8 * 8] = o;
  }
}

// ---------------- fused attention v8: counted-vmcnt pipeline + l-via-MFMA + XCD swizzle
// (blocks sharing (b,h) K/V co-reside on one XCD's L2).
__global__ __launch_bounds__(256, 3) void attn_ctx(const short* __restrict__ Q, const short* __restrict__ K,
                                                   const short* __restrict__ Vt,
                                                   float* __restrict__ rbuf, short* __restrict__ ctx) {
  __shared__ __align__(16) char smem[49152];
  short* Ks = (short*)smem;                 // [128 kpos][64 d]   swizzled, 16384 B
  short* Vs = (short*)(smem + 16384);       // [64 d][128 kpos]   swizzled, 16384 B
  short* Ps = (short*)(smem + 32768);       // [64 q][128 kpos]   swizzled, 16384 B
  short* Qs = Ps;                           // alias: Qs dead after frag hoist
  int nlin = blockIdx.x + 32 * (blockIdx.y + 16 * blockIdx.z);   // 0..2047
  int bid = (nlin & 7) * 256 + (nlin >> 3);                      // bijective (2048 % 8 == 0)
  const int q64 = bid & 31, h = (bid >> 5) & 15, b = bid >> 9;
  const int tid = threadIdx.x, w = tid >> 6, lane = tid & 63, quad = lane >> 4, l15 = lane & 15;
  const int bh = b * 16 + h, q0 = q64 * 64;

  // stage Q tile (64x64) swizzled (reg roundtrip; once per kernel)
#pragma unroll
  for (int i = 0; i < 2; ++i) {
    int c = tid + i * 256;
    int r = c >> 3, cc = c & 7;
    *(s8v*)&Qs[r * 64 + (((cc ^ (r & 7))) << 3)] =
        *(const s8v*)&Q[((b * 2048 + q0 + r) * 16 + h) * 64 + cc * 8];
  }
  __syncthreads();   // full drain: vmcnt=0 after this
  // hoist Q fragments (B-operand of St = K·Q^T), all 64 q cols
  s8v qf[4][2];
#pragma unroll
  for (int nt = 0; nt < 4; ++nt) {
    int r = nt * 16 + l15;
    qf[nt][0] = *(const s8v*)&Qs[r * 64 + ((quad ^ (r & 7)) << 3)];
    qf[nt][1] = *(const s8v*)&Qs[r * 64 + (((4 + quad) ^ (r & 7)) << 3)];
  }
  const short* kbase = &K[((long)(b * 2048) * 16 + h) * 64];
  const short* vbase = &Vt[(long)(bh * 64) * 2048];
  const int krow = w * 8 + (lane >> 3);
  const short* ksrc = kbase + krow * 1024 + (((lane & 7) ^ (lane >> 3)) << 3);
  const int vrow = w * 4 + (lane >> 4);
  const short* vsrc = vbase + vrow * 2048 + (((lane & 15) ^ vrow) << 3);
  f4v o[4] = {};
  f4v lf = {};
  s8v ones;
#pragma unroll
  for (int j = 0; j < 8; ++j) ones[j] = (short)0x3F80;   // bf16 1.0

  // prologue: issue K(0) group (4), then V(0) group (4)
#pragma unroll
  for (int i = 0; i < 4; ++i) gl_lds16(ksrc + i * 32768, &Ks[(i * 4 + w) * 512]);
#pragma unroll
  for (int i = 0; i < 4; ++i) gl_lds16(vsrc + i * 32768, &Vs[(i * 4 + w) * 512]);
  WAIT_LGKM0();   // qf reads complete before first barrier

  for (int kt = 0; kt < 16; ++kt) {
    WAIT_VM(4);                     // own K(kt) retired (V(kt) may remain)
    BAR();                          // all waves' K DMA landed
    // score phase: wave w computes St rows kpos [w*32, w*32+32), all 64 q
#pragma unroll
    for (int mt = 0; mt < 2; ++mt) {
      int kr = w * 32 + mt * 16 + l15;
      s8v a0 = *(const s8v*)&Ks[kr * 64 + ((quad ^ (kr & 7)) << 3)];
      s8v a1 = *(const s8v*)&Ks[kr * 64 + (((4 + quad) ^ (kr & 7)) << 3)];
#pragma unroll
      for (int nt = 0; nt < 4; ++nt) {
        f4v st = {};
        st = __builtin_amdgcn_mfma_f32_16x16x32_bf16(a0, qf[nt][0], st, 0, 0, 0);
        st = __builtin_amdgcn_mfma_f32_16x16x32_bf16(a1, qf[nt][1], st, 0, 0, 0);
        float e0 = fexp2(st[0]), e1 = fexp2(st[1]);
        float e2 = fexp2(st[2]), e3 = fexp2(st[3]);
        uint2 pp; pp.x = pk2(e0, e1); pp.y = pk2(e2, e3);
        int q = nt * 16 + l15;
        int chunk = (w * 4 + mt * 2 + (quad >> 1)) ^ l15;
        *(uint2*)&Ps[q * 128 + (chunk << 3) + (quad & 1) * 4] = pp;
      }
    }
    WAIT_LGKM0();                   // Ps writes + Ks reads done
    BAR();                          // Ks free, Ps visible
    if (kt < 15) {
#pragma unroll
      for (int i = 0; i < 4; ++i) gl_lds16(ksrc + (kt + 1) * 131072 + i * 32768, &Ks[(i * 4 + w) * 512]);
      WAIT_VM(4);                   // V(kt) retired (K(kt+1) outstanding)
    } else {
      WAIT_VM(0);                   // tail: only V(15) outstanding
    }
    BAR();                          // all waves' V DMA landed
    // PV phase: wave w owns q rows [w*16, w*16+16), full 128 kpos
#pragma unroll
    for (int kk = 0; kk < 4; ++kk) {
      int qr = w * 16 + l15;
      s8v a = *(const s8v*)&Ps[qr * 128 + (((kk * 4 + quad) ^ (qr & 15)) << 3)];
#pragma unroll
      for (int dt = 0; dt < 4; ++dt) {
        int d = dt * 16 + l15;
        s8v vb = *(const s8v*)&Vs[d * 128 + (((kk * 4 + quad) ^ (d & 15)) << 3)];
        o[dt] = __builtin_amdgcn_mfma_f32_16x16x32_bf16(a, vb, o[dt], 0, 0, 0);
      }
      lf = __builtin_amdgcn_mfma_f32_16x16x32_bf16(a, ones, lf, 0, 0, 0);
    }
    WAIT_LGKM0();                   // PV reads done
    BAR();                          // Vs, Ps free
    if (kt < 15) {
#pragma unroll
      for (int i = 0; i < 4; ++i) gl_lds16(vsrc + (kt + 1) * 128 + i * 32768, &Vs[(i * 4 + w) * 512]);
    }
  }

  // lf[r] = l for q = w*16 + quad*4 + r (replicated across l15). No reduce needed.
  float rv[4];
#pragma unroll
  for (int r = 0; r < 4; ++r) rv[r] = 1.0f / lf[r];
  if (l15 == 0) {
    f4v t; t[0] = rv[0]; t[1] = rv[1]; t[2] = rv[2]; t[3] = rv[3];
    *(f4v*)&rbuf[bh * 2048 + q0 + w * 16 + quad * 4] = t;
  }
#pragma unroll
  for (int dt = 0; dt < 4; ++dt)
#pragma unroll
    for (int r = 0; r < 4; ++r) {
      int sq = q0 + w * 16 + quad * 4 + r;
      ctx[((b * 2048 + sq) * 16 + h) * 64 + dt * 16 + l15] = b16(o[dt][r] * rv[r]);
    }
}

// ---------------- mean over heads of probs -> [b, q, k] fp32
// double-buffered Qs/Ks with counted vmcnt(8); rbuf preloaded; XCD swizzle so the
// 16 k-blocks sharing a Q-tile (re-read x16 heads) co-reside on one XCD's L2.
__global__ __launch_bounds__(256) void mean_probs(const short* __restrict__ Q, const short* __restrict__ K,
                                                  const float* __restrict__ rbuf, float* __restrict__ outm) {
  __shared__ __align__(16) short Qs[2][8192];   // [128 q][64 d] swizzled, dbuf
  __shared__ __align__(16) short Ks[2][8192];   // [128 k][64 d] swizzled, dbuf
  __shared__ __align__(16) float r_all[2048];   // [16 h][128 q]
  int nlin = blockIdx.x + 16 * (blockIdx.y + 16 * blockIdx.z);   // 0..1023
  int bid = (nlin & 7) * 128 + (nlin >> 3);                      // bijective (1024 % 8 == 0)
  const int k128 = bid & 15, q128 = (bid >> 4) & 15, b = bid >> 8;
  const int tid = threadIdx.x, w = tid >> 6, lane = tid & 63, quad = lane >> 4, l15 = lane & 15;
  f4v mn[2][8] = {};
  const int mrow = w * 8 + (lane >> 3);
  const int mck8 = ((lane & 7) ^ (lane >> 3)) << 3;
  const short* qsrc = Q + ((long)(b * 2048 + q128 * 128 + mrow) * 16) * 64 + mck8;
  const short* ksrc = K + ((long)(b * 2048 + k128 * 128 + mrow) * 16) * 64 + mck8;
  // preload all 16 rows of rbuf (2 issues/wave): h = i*8 + w*2 + (lane>>5), q = (lane&31)*4
  const float* rb = rbuf + (long)(b * 16) * 2048 + q128 * 128;
#pragma unroll
  for (int i = 0; i < 2; ++i) {
    int hh = i * 8 + w * 2 + (lane >> 5);
    gl_lds16((const short*)(rb + hh * 2048 + (lane & 31) * 4), (short*)r_all + (i * 4 + w) * 512);
  }
  // issue h=0 tiles into buf0 (8 loads)
#pragma unroll
  for (int i = 0; i < 4; ++i) gl_lds16(qsrc + i * 32768, &Qs[0][(i * 4 + w) * 512]);
#pragma unroll
  for (int i = 0; i < 4; ++i) gl_lds16(ksrc + i * 32768, &Ks[0][(i * 4 + w) * 512]);

  for (int h = 0; h < 16; ++h) {
    const int cur = h & 1;
    if (h < 15) {
      // issue h+1 into other buf; overlaps with this h's compute
#pragma unroll
      for (int i = 0; i < 4; ++i) gl_lds16(qsrc + (h + 1) * 64 + i * 32768, &Qs[cur ^ 1][(i * 4 + w) * 512]);
#pragma unroll
      for (int i = 0; i < 4; ++i) gl_lds16(ksrc + (h + 1) * 64 + i * 32768, &Ks[cur ^ 1][(i * 4 + w) * 512]);
      WAIT_VM(8);   // drains h's 8 (+ r_all's 2 at h=0); h+1's 8 stay in flight
    } else {
      WAIT_VM(0);
    }
    BAR();          // all waves' DMA for h landed
    s8v aq[2][2];
#pragma unroll
    for (int qt = 0; qt < 2; ++qt) {
      int r = w * 32 + qt * 16 + l15;
      aq[qt][0] = *(const s8v*)&Qs[cur][r * 64 + ((quad ^ (r & 7)) << 3)];
      aq[qt][1] = *(const s8v*)&Qs[cur][r * 64 + (((4 + quad) ^ (r & 7)) << 3)];
    }
    float rr[2][4];
#pragma unroll
    for (int qt = 0; qt < 2; ++qt)
#pragma unroll
      for (int r = 0; r < 4; ++r) rr[qt][r] = r_all[h * 128 + w * 32 + qt * 16 + quad * 4 + r];
#pragma unroll
    for (int ktile = 0; ktile < 8; ++ktile) {
      int kr = ktile * 16 + l15;
      s8v b0 = *(const s8v*)&Ks[cur][kr * 64 + ((quad ^ (kr & 7)) << 3)];
      s8v b1 = *(const s8v*)&Ks[cur][kr * 64 + (((4 + quad) ^ (kr & 7)) << 3)];
#pragma unroll
      for (int qt = 0; qt < 2; ++qt) {
        f4v sc = {};
        sc = __builtin_amdgcn_mfma_f32_16x16x32_bf16(aq[qt][0], b0, sc, 0, 0, 0);
        sc = __builtin_amdgcn_mfma_f32_16x16x32_bf16(aq[qt][1], b1, sc, 0, 0, 0);
#pragma unroll
        for (int r = 0; r < 4; ++r)
          mn[qt][ktile][r] += fexp2(sc[r]) * rr[qt][r];
      }
    }
    WAIT_LGKM0();   // this buf's reads done
    BAR();          // buf free for h+2's DMA
  }
#pragma unroll
  for (int qt = 0; qt < 2; ++qt)
#pragma unroll
    for (int ktile = 0; ktile < 8; ++ktile)
#pragma unroll
      for (int r = 0; r < 4; ++r) {
        long qrow = q128 * 128 + w * 32 + qt * 16 + quad * 4 + r;
        outm[((long)b * 2048 + qrow) * 2048 + k128 * 128 + ktile * 16 + l15] = mn[qt][ktile][r] * 0.0625f;
      }
}

extern "C" void kernel_launch(void* const* d_in, const int* in_sizes, int n_in,
                              void* d_out, int out_size, void* d_ws, size_t ws_size,
                              hipStream_t stream) {
  (void)in_sizes; (void)n_in; (void)out_size; (void)ws_size;
  const float* x  = (const float*)d_in[0];
  const float* Wq = (const float*)d_in[1];
  const float* bq = (const float*)d_in[2];
  const float* Wk = (const float*)d_in[3];
  const float* bk = (const float*)d_in[4];
  const float* Wv = (const float*)d_in[5];
  const float* bv = (const float*)d_in[6];
  const float* Wo = (const float*)d_in[7];
  const float* bo = (const float*)d_in[8];
  float* out  = (float*)d_out;
  float* outm = out + 8388608;

  char* ws = (char*)d_ws;
  short* xb  = (short*)(ws);                 // 16 MB (reused as ctx)
  short* Wqt = (short*)(ws + 16777216);      // Wqt,Wkt,Wvt,Wot contiguous 2MB each
  short* Wot = (short*)(ws + 23068672);
  short* Qb  = (short*)(ws + 25165824);      // Qb,Kb,Vb contiguous 16 MB each
  short* Kb  = (short*)(ws + 41943040);
  short* Vb  = (short*)(ws + 58720256);      // dead after vtrans
  short* Vt  = (short*)(ws + 75497472);      // 16 MB
  float* rbuf = (float*)Vb;                  // 512 KB alias in dead Vb
  short* ctx = xb;                           // alias: xb dead after QKV GEMMs

  const float C2 = 0.18033688011112042f;     // (1/8) * log2(e), folded into Q projection

  cast_f32_bf16<<<8192, 256, 0, stream>>>(x, xb, 2097152);
  wtrans4<<<dim3(512, 4), 256, 0, stream>>>(Wq, Wk, Wv, Wo, Wqt);
  gemm_qkv<<<dim3(24, 64), 256, 0, stream>>>(xb, Wqt, bq, bk, bv, Qb, C2);
  vtrans<<<dim3(16, 16, 4), 256, 0, stream>>>(Vb, Vt);
  attn_ctx<<<dim3(32, 16, 4), 256, 0, stream>>>(Qb, Kb, Vt, rbuf, ctx);
  mean_probs<<<dim3(16, 16, 4), 256, 0, stream>>>(Qb, Kb, rbuf, outm);
  gemm128<<<dim3(8, 64), 256, 0, stream>>>(ctx, Wot, bo, out);
}